// Round 3
// baseline (550.693 us; speedup 1.0000x reference)
//
#include <hip/hip_runtime.h>
#include <stdint.h>

typedef int v4i __attribute__((ext_vector_type(4)));

static constexpr int Mdim = 4096;
static constexpr int Kdim = 4096;   // IN
static constexpr int Ndim = 11008;  // OUT

#define BM 128
#define BN 128
#define BK 64

__device__ __forceinline__ void gload_lds16(const void* gp, void* lp) {
  __builtin_amdgcn_global_load_lds((const __attribute__((address_space(1))) void*)gp,
                                   (__attribute__((address_space(3))) void*)lp,
                                   16, 0, 0);
}

// ---------------- activation static quant + row sums ----------------
__global__ void k_quant(const float* __restrict__ x, const float* __restrict__ clampv,
                        signed char* __restrict__ qa, int* __restrict__ rowsum) {
  const int row = blockIdx.x;
  const int t = threadIdx.x;
  const float cv = clampv[0];
  const float a_scale = cv / 127.0f;
  const float4* xp = (const float4*)(x + (size_t)row * Kdim) + t * 4;
  int s = 0;
  int w[4];
#pragma unroll
  for (int i = 0; i < 4; ++i) {
    float4 f = xp[i];
    float q0 = fminf(fmaxf(rintf(fminf(fmaxf(f.x, -cv), cv) / a_scale), -127.f), 127.f);
    float q1 = fminf(fmaxf(rintf(fminf(fmaxf(f.y, -cv), cv) / a_scale), -127.f), 127.f);
    float q2 = fminf(fmaxf(rintf(fminf(fmaxf(f.z, -cv), cv) / a_scale), -127.f), 127.f);
    float q3 = fminf(fmaxf(rintf(fminf(fmaxf(f.w, -cv), cv) / a_scale), -127.f), 127.f);
    int i0 = (int)q0, i1 = (int)q1, i2 = (int)q2, i3 = (int)q3;
    s += i0 + i1 + i2 + i3;
    w[i] = (i0 & 255) | ((i1 & 255) << 8) | ((i2 & 255) << 16) | ((i3 & 255) << 24);
  }
  ((int4*)(qa + (size_t)row * Kdim))[t] = make_int4(w[0], w[1], w[2], w[3]);
#pragma unroll
  for (int off = 32; off > 0; off >>= 1) s += __shfl_down(s, off, 64);
  __shared__ int red[4];
  if ((t & 63) == 0) red[t >> 6] = s;
  __syncthreads();
  if (t == 0) rowsum[row] = red[0] + red[1] + red[2] + red[3];
}

// ---------------- int4 unpack: [N][K/2] int32 -> [N][K] int8 ----------------
__global__ void k_unpack(const int4* __restrict__ qw, uint2* __restrict__ wb) {
  const int idx = blockIdx.x * 256 + threadIdx.x;
  int4 q = qw[idx];
  uint2 r;
  r.x = (unsigned)(((q.x >> 4) & 15) | ((q.x & 15) << 8) |
                   (((q.y >> 4) & 15) << 16) | ((q.y & 15) << 24));
  r.y = (unsigned)(((q.z >> 4) & 15) | ((q.z & 15) << 8) |
                   (((q.w >> 4) & 15) << 16) | ((q.w & 15) << 24));
  wb[idx] = r;
}

// ---------------- int8 GEMM: BK=64, LDS double-buffer, 1 barrier/iter ----------------
// Swizzle: 16B-chunk c of row r stored at LDS pos c ^ ((r>>1)&3)
//   -> 8-lane b128 phases hit 8 distinct bank-quads (worst 2-way = free).
__global__ __launch_bounds__(256) void k_gemm(
    const signed char* __restrict__ A, const signed char* __restrict__ B,
    const float* __restrict__ scales, const int* __restrict__ qzeros,
    const float* __restrict__ bias, const float* __restrict__ clampv,
    const int* __restrict__ rowsum, float* __restrict__ out) {
  __shared__ signed char As[2][BM * BK];  // 2 x 8 KB
  __shared__ signed char Bs[2][BN * BK];  // 2 x 8 KB
  const int t = threadIdx.x;
  const int lane = t & 63;
  const int wave = t >> 6;
  const int wm = (wave >> 1) * 64;
  const int wn = (wave & 1) * 64;

  // grouped tile mapping: G=16 along M, M-fastest within group.
  // concurrent ~256 blocks cover 16mt x 16nt -> 16 MB working set.
  const int lin = blockIdx.x;                 // grid is 1D, 2752 blocks
  const int group = lin / (16 * 86);          // 2 groups of 16 mt
  const int rem = lin - group * (16 * 86);
  const int m0 = (group * 16 + (rem & 15)) * BM;
  const int n0 = (rem >> 4) * BN;

  // staging: thread t covers rows srow, srow+64; LDS pos t&3; swizzled global chunk.
  const int srow = t >> 2;
  const int schunk = (t & 3) ^ ((srow >> 1) & 3);
  const signed char* gA0 = A + (size_t)(m0 + srow) * Kdim + schunk * 16;
  const signed char* gB0 = B + (size_t)(n0 + srow) * Kdim + schunk * 16;

  v4i acc[4][4] = {};
  const int col = lane & 15;
  const int q16 = lane >> 4;                       // k-chunk 0..3 within BK=64
  const int pos = (q16 ^ ((col >> 1) & 3)) * 16;   // (row>>1)&3 == (col>>1)&3 for frag rows

  auto stage = [&](int buf, int k0) {
    gload_lds16(gA0 + k0, &As[buf][t * 16]);
    gload_lds16(gA0 + (size_t)64 * Kdim + k0, &As[buf][4096 + t * 16]);
    gload_lds16(gB0 + k0, &Bs[buf][t * 16]);
    gload_lds16(gB0 + (size_t)64 * Kdim + k0, &Bs[buf][4096 + t * 16]);
  };
  auto compute = [&](int buf) {
    v4i av[4], bv[4];
#pragma unroll
    for (int i = 0; i < 4; ++i)
      av[i] = *(const v4i*)&As[buf][(wm + i * 16 + col) * BK + pos];
#pragma unroll
    for (int i = 0; i < 4; ++i)
      bv[i] = *(const v4i*)&Bs[buf][(wn + i * 16 + col) * BK + pos];
#pragma unroll
    for (int i = 0; i < 4; ++i)
#pragma unroll
      for (int j = 0; j < 4; ++j)
        acc[i][j] = __builtin_amdgcn_mfma_i32_16x16x64_i8(av[i], bv[j], acc[i][j], 0, 0, 0);
  };

  stage(0, 0);
  for (int k0 = 0; k0 < Kdim; k0 += 2 * BK) {
    __syncthreads();                    // vmcnt drain: tile(buf0) ready; buf1 free
    if (k0 + BK < Kdim) stage(1, k0 + BK);        // prefetch hidden behind compute
    compute(0);
    __syncthreads();
    if (k0 + 2 * BK < Kdim) stage(0, k0 + 2 * BK);
    compute(1);
  }

  // epilogue: out = a_scale*scale[n]*(acc - qz[n]*rowsum[m]) + bias[n]
  const float a_scale = clampv[0] / 127.0f;
  const int rq = (lane >> 4) * 4;
  int rs[4][4];
#pragma unroll
  for (int i = 0; i < 4; ++i)
#pragma unroll
    for (int r = 0; r < 4; ++r)
      rs[i][r] = rowsum[m0 + wm + i * 16 + rq + r];
#pragma unroll
  for (int j = 0; j < 4; ++j) {
    const int n = n0 + wn + j * 16 + col;
    const float sn = scales[n] * a_scale;
    const int zn = qzeros[n];
    const float bn = bias[n];
#pragma unroll
    for (int i = 0; i < 4; ++i) {
      const int mb = m0 + wm + i * 16 + rq;
#pragma unroll
      for (int r = 0; r < 4; ++r) {
        const int iv = acc[i][j][r] - zn * rs[i][r];
        out[(size_t)(mb + r) * Ndim + n] = (float)iv * sn + bn;
      }
    }
  }
}

extern "C" void kernel_launch(void* const* d_in, const int* in_sizes, int n_in,
                              void* d_out, int out_size, void* d_ws, size_t ws_size,
                              hipStream_t stream) {
  const float* x  = (const float*)d_in[0];
  const int* qw   = (const int*)d_in[1];
  const int* qz   = (const int*)d_in[2];
  const float* sc = (const float*)d_in[3];
  const float* bi = (const float*)d_in[4];
  const float* cv = (const float*)d_in[5];
  float* out = (float*)d_out;

  signed char* qa = (signed char*)d_ws;
  signed char* wb = qa + (size_t)Mdim * Kdim;
  int* rowsum = (int*)(wb + (size_t)Ndim * Kdim);

  k_quant<<<Mdim, 256, 0, stream>>>(x, cv, qa, rowsum);
  k_unpack<<<(Ndim * (Kdim / 2) / 4) / 256, 256, 0, stream>>>((const int4*)qw, (uint2*)wb);
  k_gemm<<<(Mdim / BM) * (Ndim / BN), 256, 0, stream>>>(qa, wb, sc, qz, bi, cv, rowsum, out);
}